// Round 4
// baseline (85.020 us; speedup 1.0000x reference)
//
#include <hip/hip_runtime.h>

#define N_NUM 64
#define N_CAT 32
#define CAT_W 8
#define N_ICD 128
#define BATCH 131072

// W layout (2 x 448): [0:64)=num, [64:320)=cat (32x8), [320:448)=icd
// M layout (2 x 224): [0:64)=num, [64:96)=cat,         [96:224)=icd
#define WROW 448
#define MROW 224

typedef float f4 __attribute__((ext_vector_type(4)));

__device__ __forceinline__ float fast_tanh(float x) {
    // tanh(x) = 1 - 2/(exp(2x)+1); native exp & rcp saturate correctly at +-inf
    float e = __expf(2.0f * x);
    return 1.0f - 2.0f * __builtin_amdgcn_rcpf(e + 1.0f);
}

// 4 waves/block; wave w owns feature-quarter w; each thread handles 2 adjacent
// batch elems. cat_x (128 MiB) is loaded NON-TEMPORAL so it streams through
// L2/L3 evict-first, leaving num+icd (96 MiB) resident in the 256 MiB L3
// across graph replays.
__global__ void __launch_bounds__(256, 8)
phenotype_softmax_kernel(const float* __restrict__ num_x,
                         const float* __restrict__ cat_x,
                         const float* __restrict__ icd_x,
                         const float* __restrict__ W,
                         const float* __restrict__ M,
                         float* __restrict__ out) {
    __shared__ float4 sNum[N_NUM];        // {W0, W1, M0, M1}
    __shared__ float4 sIcd[N_ICD];        // {W0, W1, M0, M1}
    __shared__ float4 sCatW[N_CAT][4];    // per g: {W0[w],W1[w],W0[w+1],W1[w+1]} w=0,2,4,6
    __shared__ float2 sCatM[N_CAT];       // {M0, M1}
    __shared__ float2 sPart[4][128];      // per-wave partial (f0,f1), elem-major

    const int t = threadIdx.x;

    if (t < N_NUM) {
        sNum[t] = make_float4(W[t], W[WROW + t], M[t], M[MROW + t]);
    }
    if (t < N_ICD) {
        sIcd[t] = make_float4(W[320 + t], W[WROW + 320 + t],
                              M[96 + t],  M[MROW + 96 + t]);
    }
    if (t < N_CAT * 4) {  // g = t/4, quad q covers w=2q,2q+1
        int g = t >> 2, q = t & 3, w = 2 * q;
        int base = 64 + g * 8 + w;
        sCatW[g][q] = make_float4(W[base],     W[WROW + base],
                                  W[base + 1], W[WROW + base + 1]);
    }
    if (t < N_CAT) {
        sCatM[t] = make_float2(M[64 + t], M[MROW + 64 + t]);
    }
    __syncthreads();

    const int wave = t >> 6;
    const int lane = t & 63;
    const int b0   = blockIdx.x * 128 + 2 * lane;   // first of the 2 elems

    float f0a = 0.0f, f1a = 0.0f;   // elem b0
    float f0b = 0.0f, f1b = 0.0f;   // elem b0+1

    // ---- numerical: 16 features for this wave, float2 per feature ----
    const int n0 = wave * 16;
#pragma unroll
    for (int i = 0; i < 16; ++i) {
        int n = n0 + i;
        float2 x = *reinterpret_cast<const float2*>(num_x + (size_t)n * BATCH + b0);
        float4 c = sNum[n];
        f0a = fmaf(c.z, fast_tanh(c.x * x.x), f0a);
        f1a = fmaf(c.w, fast_tanh(c.y * x.x), f1a);
        f0b = fmaf(c.z, fast_tanh(c.x * x.y), f0b);
        f1b = fmaf(c.w, fast_tanh(c.y * x.y), f1b);
    }

    // ---- categorical: 8 groups for this wave, 4x NON-TEMPORAL float4 ----
    const int g0 = wave * 8;
#pragma unroll
    for (int i = 0; i < 8; ++i) {
        int g = g0 + i;
        const f4* vp = reinterpret_cast<const f4*>(cat_x + ((size_t)g * BATCH + b0) * CAT_W);
        f4 va0 = __builtin_nontemporal_load(vp + 0);   // elem b0,   w 0..3
        f4 va1 = __builtin_nontemporal_load(vp + 1);   // elem b0,   w 4..7
        f4 vb0 = __builtin_nontemporal_load(vp + 2);   // elem b0+1, w 0..3
        f4 vb1 = __builtin_nontemporal_load(vp + 3);   // elem b0+1, w 4..7
        float4 p0 = sCatW[g][0];
        float4 p1 = sCatW[g][1];
        float4 p2 = sCatW[g][2];
        float4 p3 = sCatW[g][3];
        float sa0, sa1, sb0, sb1;
        sa0 = va0.x * p0.x;             sa1 = va0.x * p0.y;
        sb0 = vb0.x * p0.x;             sb1 = vb0.x * p0.y;
        sa0 = fmaf(va0.y, p0.z, sa0);   sa1 = fmaf(va0.y, p0.w, sa1);
        sb0 = fmaf(vb0.y, p0.z, sb0);   sb1 = fmaf(vb0.y, p0.w, sb1);
        sa0 = fmaf(va0.z, p1.x, sa0);   sa1 = fmaf(va0.z, p1.y, sa1);
        sb0 = fmaf(vb0.z, p1.x, sb0);   sb1 = fmaf(vb0.z, p1.y, sb1);
        sa0 = fmaf(va0.w, p1.z, sa0);   sa1 = fmaf(va0.w, p1.w, sa1);
        sb0 = fmaf(vb0.w, p1.z, sb0);   sb1 = fmaf(vb0.w, p1.w, sb1);
        sa0 = fmaf(va1.x, p2.x, sa0);   sa1 = fmaf(va1.x, p2.y, sa1);
        sb0 = fmaf(vb1.x, p2.x, sb0);   sb1 = fmaf(vb1.x, p2.y, sb1);
        sa0 = fmaf(va1.y, p2.z, sa0);   sa1 = fmaf(va1.y, p2.w, sa1);
        sb0 = fmaf(vb1.y, p2.z, sb0);   sb1 = fmaf(vb1.y, p2.w, sb1);
        sa0 = fmaf(va1.z, p3.x, sa0);   sa1 = fmaf(va1.z, p3.y, sa1);
        sb0 = fmaf(vb1.z, p3.x, sb0);   sb1 = fmaf(vb1.z, p3.y, sb1);
        sa0 = fmaf(va1.w, p3.z, sa0);   sa1 = fmaf(va1.w, p3.w, sa1);
        sb0 = fmaf(vb1.w, p3.z, sb0);   sb1 = fmaf(vb1.w, p3.w, sb1);
        float2 m = sCatM[g];
        f0a = fmaf(m.x, fast_tanh(sa0), f0a);
        f1a = fmaf(m.y, fast_tanh(sa1), f1a);
        f0b = fmaf(m.x, fast_tanh(sb0), f0b);
        f1b = fmaf(m.y, fast_tanh(sb1), f1b);
    }

    // ---- icd: 32 features for this wave, float2 per feature ----
    const int m0 = wave * 32;
#pragma unroll
    for (int i = 0; i < 32; ++i) {
        int n = m0 + i;
        float2 x = *reinterpret_cast<const float2*>(icd_x + (size_t)n * BATCH + b0);
        float4 c = sIcd[n];
        f0a = fmaf(c.z, fast_tanh(c.x * x.x), f0a);
        f1a = fmaf(c.w, fast_tanh(c.y * x.x), f1a);
        f0b = fmaf(c.z, fast_tanh(c.x * x.y), f0b);
        f1b = fmaf(c.w, fast_tanh(c.y * x.y), f1b);
    }

    sPart[wave][2 * lane]     = make_float2(f0a, f1a);
    sPart[wave][2 * lane + 1] = make_float2(f0b, f1b);
    __syncthreads();

    // ---- cross-wave reduce + 2-class softmax: first 128 threads, 1 elem each ----
    if (t < 128) {
        float2 p0 = sPart[0][t];
        float2 p1 = sPart[1][t];
        float2 p2 = sPart[2][t];
        float2 p3 = sPart[3][t];
        float a0 = (p0.x + p1.x) + (p2.x + p3.x);
        float a1 = (p0.y + p1.y) + (p2.y + p3.y);
        float d  = a0 - a1;
        float e0 = __expf(-d);
        float e1 = __expf(d);
        int bb = blockIdx.x * 128 + t;
        out[bb]         = __builtin_amdgcn_rcpf(1.0f + e0);
        out[BATCH + bb] = __builtin_amdgcn_rcpf(1.0f + e1);
    }
}

extern "C" void kernel_launch(void* const* d_in, const int* in_sizes, int n_in,
                              void* d_out, int out_size, void* d_ws, size_t ws_size,
                              hipStream_t stream) {
    const float* num_x = (const float*)d_in[0];
    const float* cat_x = (const float*)d_in[1];
    const float* icd_x = (const float*)d_in[2];
    const float* W     = (const float*)d_in[3];
    const float* M     = (const float*)d_in[4];
    float* out = (float*)d_out;

    dim3 block(256);
    dim3 grid(BATCH / 128);  // 1024 blocks
    phenotype_softmax_kernel<<<grid, block, 0, stream>>>(num_x, cat_x, icd_x, W, M, out);
}

// Round 5
// 48.100 us; speedup vs baseline: 1.7676x; 1.7676x over previous
//
#include <hip/hip_runtime.h>

#define N_NUM 64
#define N_CAT 32
#define CAT_W 8
#define N_ICD 128
#define BATCH 131072

// W layout (2 x 448): [0:64)=num, [64:320)=cat (32x8), [320:448)=icd
// M layout (2 x 224): [0:64)=num, [64:96)=cat,         [96:224)=icd
#define WROW 448
#define MROW 224

__device__ __forceinline__ float fast_tanh(float x) {
    // tanh(x) = 1 - 2/(exp(2x)+1); native exp & rcp saturate correctly at +-inf
    float e = __expf(2.0f * x);
    return 1.0f - 2.0f * __builtin_amdgcn_rcpf(e + 1.0f);
}

// 4 waves/block; wave w owns feature-quarter w; each thread handles 2 adjacent
// batch elements. Explicit 2-deep load-batch / compute software pipeline:
// issue the next batch's global loads BEFORE computing the current batch, so
// ~64 VGPRs (16+ cache lines) of loads are in flight per wave at all times.
__global__ void __launch_bounds__(256, 4)
phenotype_softmax_kernel(const float* __restrict__ num_x,
                         const float* __restrict__ cat_x,
                         const float* __restrict__ icd_x,
                         const float* __restrict__ W,
                         const float* __restrict__ M,
                         float* __restrict__ out) {
    __shared__ float4 sNum[N_NUM];        // {W0, W1, M0, M1}
    __shared__ float4 sIcd[N_ICD];        // {W0, W1, M0, M1}
    __shared__ float4 sCatW[N_CAT][4];    // per g: {W0[w],W1[w],W0[w+1],W1[w+1]} w=0,2,4,6
    __shared__ float2 sCatM[N_CAT];       // {M0, M1}
    __shared__ float2 sPart[4][128];      // per-wave partial (f0,f1), elem-major

    const int t = threadIdx.x;

    if (t < N_NUM) {
        sNum[t] = make_float4(W[t], W[WROW + t], M[t], M[MROW + t]);
    }
    if (t < N_ICD) {
        sIcd[t] = make_float4(W[320 + t], W[WROW + 320 + t],
                              M[96 + t],  M[MROW + 96 + t]);
    }
    if (t < N_CAT * 4) {  // g = t/4, quad q covers w=2q,2q+1
        int g = t >> 2, q = t & 3, w = 2 * q;
        int base = 64 + g * 8 + w;
        sCatW[g][q] = make_float4(W[base],     W[WROW + base],
                                  W[base + 1], W[WROW + base + 1]);
    }
    if (t < N_CAT) {
        sCatM[t] = make_float2(M[64 + t], M[MROW + 64 + t]);
    }
    __syncthreads();

    const int wave = t >> 6;
    const int lane = t & 63;
    const int b0   = blockIdx.x * 128 + 2 * lane;   // first of the 2 elems

    float f0a = 0.0f, f1a = 0.0f;   // elem b0
    float f0b = 0.0f, f1b = 0.0f;   // elem b0+1

    const int n0 = wave * 16;   // numerical base feature
    const int g0 = wave * 8;    // categorical base group
    const int m0 = wave * 32;   // icd base feature

    const float* numP = num_x + (size_t)n0 * BATCH + b0;
    const float* icdP = icd_x + (size_t)m0 * BATCH + b0;
    const float4* catP = reinterpret_cast<const float4*>(cat_x) + ((size_t)g0 * BATCH + b0) * 2;
    const size_t CATG = (size_t)BATCH * 2;   // float4s per group row

    // ---------------- load/compute macros (all indices compile-time) --------
#define NUM_LOAD()                                                             \
    _Pragma("unroll")                                                          \
    for (int i = 0; i < 16; ++i)                                               \
        xn[i] = *reinterpret_cast<const float2*>(numP + (size_t)i * BATCH);

#define NUM_COMP()                                                             \
    _Pragma("unroll")                                                          \
    for (int i = 0; i < 16; ++i) {                                             \
        float4 c = sNum[n0 + i];                                               \
        f0a = fmaf(c.z, fast_tanh(c.x * xn[i].x), f0a);                        \
        f1a = fmaf(c.w, fast_tanh(c.y * xn[i].x), f1a);                        \
        f0b = fmaf(c.z, fast_tanh(c.x * xn[i].y), f0b);                        \
        f1b = fmaf(c.w, fast_tanh(c.y * xn[i].y), f1b);                        \
    }

    // one cat buffer = 2 groups x 4 float4
#define CAT_LOAD(buf, gg)                                                      \
    _Pragma("unroll")                                                          \
    for (int j = 0; j < 2; ++j) {                                              \
        const float4* vp = catP + (size_t)((gg) + j) * CATG;                   \
        buf[j][0] = vp[0]; buf[j][1] = vp[1];                                  \
        buf[j][2] = vp[2]; buf[j][3] = vp[3];                                  \
    }

#define CAT_COMP(buf, gg)                                                      \
    _Pragma("unroll")                                                          \
    for (int j = 0; j < 2; ++j) {                                              \
        int g = g0 + (gg) + j;                                                 \
        float4 va0 = buf[j][0], va1 = buf[j][1];                               \
        float4 vb0 = buf[j][2], vb1 = buf[j][3];                               \
        float4 p0 = sCatW[g][0], p1 = sCatW[g][1];                             \
        float4 p2 = sCatW[g][2], p3 = sCatW[g][3];                             \
        float sa0, sa1, sb0, sb1;                                              \
        sa0 = va0.x * p0.x;             sa1 = va0.x * p0.y;                    \
        sb0 = vb0.x * p0.x;             sb1 = vb0.x * p0.y;                    \
        sa0 = fmaf(va0.y, p0.z, sa0);   sa1 = fmaf(va0.y, p0.w, sa1);          \
        sb0 = fmaf(vb0.y, p0.z, sb0);   sb1 = fmaf(vb0.y, p0.w, sb1);          \
        sa0 = fmaf(va0.z, p1.x, sa0);   sa1 = fmaf(va0.z, p1.y, sa1);          \
        sb0 = fmaf(vb0.z, p1.x, sb0);   sb1 = fmaf(vb0.z, p1.y, sb1);          \
        sa0 = fmaf(va0.w, p1.z, sa0);   sa1 = fmaf(va0.w, p1.w, sa1);          \
        sb0 = fmaf(vb0.w, p1.z, sb0);   sb1 = fmaf(vb0.w, p1.w, sb1);          \
        sa0 = fmaf(va1.x, p2.x, sa0);   sa1 = fmaf(va1.x, p2.y, sa1);          \
        sb0 = fmaf(vb1.x, p2.x, sb0);   sb1 = fmaf(vb1.x, p2.y, sb1);          \
        sa0 = fmaf(va1.y, p2.z, sa0);   sa1 = fmaf(va1.y, p2.w, sa1);          \
        sb0 = fmaf(vb1.y, p2.z, sb0);   sb1 = fmaf(vb1.y, p2.w, sb1);          \
        sa0 = fmaf(va1.z, p3.x, sa0);   sa1 = fmaf(va1.z, p3.y, sa1);          \
        sb0 = fmaf(vb1.z, p3.x, sb0);   sb1 = fmaf(vb1.z, p3.y, sb1);          \
        sa0 = fmaf(va1.w, p3.z, sa0);   sa1 = fmaf(va1.w, p3.w, sa1);          \
        sb0 = fmaf(vb1.w, p3.z, sb0);   sb1 = fmaf(vb1.w, p3.w, sb1);          \
        float2 m = sCatM[g];                                                   \
        f0a = fmaf(m.x, fast_tanh(sa0), f0a);                                  \
        f1a = fmaf(m.y, fast_tanh(sa1), f1a);                                  \
        f0b = fmaf(m.x, fast_tanh(sb0), f0b);                                  \
        f1b = fmaf(m.y, fast_tanh(sb1), f1b);                                  \
    }

    // one icd buffer = 16 features x float2
#define ICD_LOAD(buf, ff)                                                      \
    _Pragma("unroll")                                                          \
    for (int i = 0; i < 16; ++i)                                               \
        buf[i] = *reinterpret_cast<const float2*>(icdP + (size_t)((ff) + i) * BATCH);

#define ICD_COMP(buf, ff)                                                      \
    _Pragma("unroll")                                                          \
    for (int i = 0; i < 16; ++i) {                                             \
        float4 c = sIcd[m0 + (ff) + i];                                        \
        f0a = fmaf(c.z, fast_tanh(c.x * buf[i].x), f0a);                       \
        f1a = fmaf(c.w, fast_tanh(c.y * buf[i].x), f1a);                       \
        f0b = fmaf(c.z, fast_tanh(c.x * buf[i].y), f0b);                       \
        f1b = fmaf(c.w, fast_tanh(c.y * buf[i].y), f1b);                       \
    }

    // ---------------- software-pipelined schedule ---------------------------
    float2 xn[16];
    float4 cA[2][4], cB[2][4];
    float2 iA[16], iB[16];

    NUM_LOAD();            // 16 float2 in flight
    CAT_LOAD(cA, 0);       // +8 float4
    NUM_COMP();
    CAT_LOAD(cB, 2);
    CAT_COMP(cA, 0);
    CAT_LOAD(cA, 4);
    CAT_COMP(cB, 2);
    CAT_LOAD(cB, 6);
    CAT_COMP(cA, 4);
    ICD_LOAD(iA, 0);
    CAT_COMP(cB, 6);
    ICD_LOAD(iB, 16);
    ICD_COMP(iA, 0);
    ICD_COMP(iB, 16);

    sPart[wave][2 * lane]     = make_float2(f0a, f1a);
    sPart[wave][2 * lane + 1] = make_float2(f0b, f1b);
    __syncthreads();

    // ---- cross-wave reduce + 2-class softmax: first 128 threads, 1 elem each
    if (t < 128) {
        float2 p0 = sPart[0][t];
        float2 p1 = sPart[1][t];
        float2 p2 = sPart[2][t];
        float2 p3 = sPart[3][t];
        float a0 = (p0.x + p1.x) + (p2.x + p3.x);
        float a1 = (p0.y + p1.y) + (p2.y + p3.y);
        float d  = a0 - a1;
        float e0 = __expf(-d);
        float e1 = __expf(d);
        int bb = blockIdx.x * 128 + t;
        out[bb]         = __builtin_amdgcn_rcpf(1.0f + e0);
        out[BATCH + bb] = __builtin_amdgcn_rcpf(1.0f + e1);
    }
}

extern "C" void kernel_launch(void* const* d_in, const int* in_sizes, int n_in,
                              void* d_out, int out_size, void* d_ws, size_t ws_size,
                              hipStream_t stream) {
    const float* num_x = (const float*)d_in[0];
    const float* cat_x = (const float*)d_in[1];
    const float* icd_x = (const float*)d_in[2];
    const float* W     = (const float*)d_in[3];
    const float* M     = (const float*)d_in[4];
    float* out = (float*)d_out;

    dim3 block(256);
    dim3 grid(BATCH / 128);  // 1024 blocks
    phenotype_softmax_kernel<<<grid, block, 0, stream>>>(num_x, cat_x, icd_x, W, M, out);
}

// Round 6
// 44.601 us; speedup vs baseline: 1.9062x; 1.0785x over previous
//
#include <hip/hip_runtime.h>

#define N_NUM 64
#define N_CAT 32
#define CAT_W 8
#define N_ICD 128
#define BATCH 131072

// W layout (2 x 448): [0:64)=num, [64:320)=cat (32x8), [320:448)=icd
// M layout (2 x 224): [0:64)=num, [64:96)=cat,         [96:224)=icd
#define WROW 448
#define MROW 224

__device__ __forceinline__ float fast_tanh(float x) {
    // tanh(x) = 1 - 2/(exp(2x)+1); native exp & rcp saturate correctly at +-inf
    float e = __expf(2.0f * x);
    return 1.0f - 2.0f * __builtin_amdgcn_rcpf(e + 1.0f);
}

// Best measured variant (R2, 44.7 us = ~5.3 TB/s aggregate input rate, ~84% of
// the 6.29 TB/s demonstrated copy ceiling). 4 waves/block; wave w handles
// feature-quarter w for 64 batch elems; cross-wave reduce in LDS.
// Per-thread bytes: num 16*4 + cat 8*32 + icd 32*4 = 448 B (balanced).
// Proven-null levers on this problem: occupancy 21->73% (R2), 2 elems/thread +
// wider loads (R3), nt streaming (R4, 2x WORSE), explicit SW pipeline (R5).
__global__ void __launch_bounds__(256, 8)
phenotype_softmax_kernel(const float* __restrict__ num_x,
                         const float* __restrict__ cat_x,
                         const float* __restrict__ icd_x,
                         const float* __restrict__ W,
                         const float* __restrict__ M,
                         float* __restrict__ out) {
    __shared__ float4 sNum[N_NUM];        // {W0, W1, M0, M1}
    __shared__ float4 sIcd[N_ICD];        // {W0, W1, M0, M1}
    __shared__ float4 sCatW[N_CAT][4];    // per g: {W0[w],W1[w],W0[w+1],W1[w+1]} w=0,2,4,6
    __shared__ float2 sCatM[N_CAT];       // {M0, M1}
    __shared__ float2 sPart[4][64];       // per-wave partial (f0,f1) per batch elem

    const int t = threadIdx.x;

    if (t < N_NUM) {
        sNum[t] = make_float4(W[t], W[WROW + t], M[t], M[MROW + t]);
    }
    if (t < N_ICD) {
        sIcd[t] = make_float4(W[320 + t], W[WROW + 320 + t],
                              M[96 + t],  M[MROW + 96 + t]);
    }
    if (t < N_CAT * 4) {  // 128 threads: g = t/4, quad q covers w=2q,2q+1
        int g = t >> 2, q = t & 3, w = 2 * q;
        int base = 64 + g * 8 + w;
        sCatW[g][q] = make_float4(W[base],     W[WROW + base],
                                  W[base + 1], W[WROW + base + 1]);
    }
    if (t < N_CAT) {
        sCatM[t] = make_float2(M[64 + t], M[MROW + 64 + t]);
    }
    __syncthreads();

    const int wave = t >> 6;
    const int lane = t & 63;
    const int b    = blockIdx.x * 64 + lane;

    float f0 = 0.0f, f1 = 0.0f;

    // ---- numerical: 16 features for this wave ----
    const int n0 = wave * 16;
#pragma unroll
    for (int i = 0; i < 16; ++i) {
        int n = n0 + i;
        float x = num_x[(size_t)n * BATCH + b];
        float4 c = sNum[n];
        f0 = fmaf(c.z, fast_tanh(c.x * x), f0);
        f1 = fmaf(c.w, fast_tanh(c.y * x), f1);
    }

    // ---- categorical: 8 groups for this wave, 2x float4 per group ----
    const int g0 = wave * 8;
#pragma unroll
    for (int i = 0; i < 8; ++i) {
        int g = g0 + i;
        const float4* vp = reinterpret_cast<const float4*>(cat_x + ((size_t)g * BATCH + b) * CAT_W);
        float4 v0 = vp[0];
        float4 v1 = vp[1];
        float4 p0 = sCatW[g][0];
        float4 p1 = sCatW[g][1];
        float4 p2 = sCatW[g][2];
        float4 p3 = sCatW[g][3];
        float s0, s1;
        s0 = v0.x * p0.x;            s1 = v0.x * p0.y;
        s0 = fmaf(v0.y, p0.z, s0);   s1 = fmaf(v0.y, p0.w, s1);
        s0 = fmaf(v0.z, p1.x, s0);   s1 = fmaf(v0.z, p1.y, s1);
        s0 = fmaf(v0.w, p1.z, s0);   s1 = fmaf(v0.w, p1.w, s1);
        s0 = fmaf(v1.x, p2.x, s0);   s1 = fmaf(v1.x, p2.y, s1);
        s0 = fmaf(v1.y, p2.z, s0);   s1 = fmaf(v1.y, p2.w, s1);
        s0 = fmaf(v1.z, p3.x, s0);   s1 = fmaf(v1.z, p3.y, s1);
        s0 = fmaf(v1.w, p3.z, s0);   s1 = fmaf(v1.w, p3.w, s1);
        float2 m = sCatM[g];
        f0 = fmaf(m.x, fast_tanh(s0), f0);
        f1 = fmaf(m.y, fast_tanh(s1), f1);
    }

    // ---- icd: 32 features for this wave ----
    const int m0 = wave * 32;
#pragma unroll
    for (int i = 0; i < 32; ++i) {
        int n = m0 + i;
        float x = icd_x[(size_t)n * BATCH + b];
        float4 c = sIcd[n];
        f0 = fmaf(c.z, fast_tanh(c.x * x), f0);
        f1 = fmaf(c.w, fast_tanh(c.y * x), f1);
    }

    sPart[wave][lane] = make_float2(f0, f1);
    __syncthreads();

    // ---- cross-wave reduce + 2-class softmax, wave 0 only ----
    if (t < 64) {
        float2 p0 = sPart[0][t];
        float2 p1 = sPart[1][t];
        float2 p2 = sPart[2][t];
        float2 p3 = sPart[3][t];
        float a0 = p0.x + p1.x + p2.x + p3.x;
        float a1 = p0.y + p1.y + p2.y + p3.y;
        float d  = a0 - a1;
        float e0 = __expf(-d);
        float e1 = __expf(d);
        int bb = blockIdx.x * 64 + t;
        out[bb]         = __builtin_amdgcn_rcpf(1.0f + e0);
        out[BATCH + bb] = __builtin_amdgcn_rcpf(1.0f + e1);
    }
}

extern "C" void kernel_launch(void* const* d_in, const int* in_sizes, int n_in,
                              void* d_out, int out_size, void* d_ws, size_t ws_size,
                              hipStream_t stream) {
    const float* num_x = (const float*)d_in[0];
    const float* cat_x = (const float*)d_in[1];
    const float* icd_x = (const float*)d_in[2];
    const float* W     = (const float*)d_in[3];
    const float* M     = (const float*)d_in[4];
    float* out = (float*)d_out;

    dim3 block(256);
    dim3 grid(BATCH / 64);  // 2048 blocks = 8 blocks/CU
    phenotype_softmax_kernel<<<grid, block, 0, stream>>>(num_x, cat_x, icd_x, W, M, out);
}